// Round 8
// baseline (146.046 us; speedup 1.0000x reference)
//
#include <hip/hip_runtime.h>
#include <stdint.h>

// conv_59700045414486: y[b,n,o] = sum_{k,c} x[b, kernel2[n,k], c] * W[k,c,o] + bias[o]
// B=64, N=4096, C=64, OUT=64, K2=4
//
// R13: R12 (register-path gathers) faulted. Diagnosis: (1) rule-#18 unsound-
// ness — "memory" clobber does not order register-only consumers past the
// inline-asm vmcnt waits; (2) rule-#20 exposure — 176 VGPRs of arrays hinged
// on one #pragma unroll 16; any scratch spill injects hidden vmem ops that
// break the exact vmcnt ledger -> stale address register -> page fault.
// This round keeps the experiment (per-lane global_load_dwordx4 gathers into
// registers, VMEM/MSHR path, testing escape from the ~117cy/instr LDS-DMA
// serialization wall) but sound:
//   - sched_barrier(0) after every counted wait (pins consumers below it);
//   - 16 pipeline steps MACRO-expanded: every array index a literal;
//   - idx in 512B LDS, read per-issue via ds_read (lgkmcnt; vmcnt ledger
//     untouched), VGPR ~270 -> no spill possible at launch_bounds(64,1);
//   - 3 rotating 8xf32x4 staging buffers, prefetch distance 2 half-tiles;
//   - R10 locality mapping kept (XCD k <-> batch-group, FETCH ~50MB).

#define N_SITES  4096
#define C_DIM    64
#define OUT_DIM  64

typedef __attribute__((ext_vector_type(8))) short bf16x8;
typedef __attribute__((ext_vector_type(4))) float f32x4;

__device__ __forceinline__ uint32_t pack2_bf16(float f0, float f1) {
    uint32_t u0 = __float_as_uint(f0) + 0x8000u;
    uint32_t u1 = __float_as_uint(f1) + 0x8000u;
    return __builtin_amdgcn_perm(u1, u0, 0x07060302u);  // [bf16(f1)|bf16(f0)]
}

template<int N> __device__ __forceinline__ void wait_vmcnt() {
    asm volatile("s_waitcnt vmcnt(%0)" :: "n"(N) : "memory");
}

// per-lane 16B global load into explicit VGPRs; manual vmcnt discipline.
template<int OFF>
__device__ __forceinline__ void gld16(f32x4& d, const float* p) {
    asm volatile("global_load_dwordx4 %0, %1, off offset:%2"
                 : "=v"(d) : "v"(p), "n"(OFF) : "memory");
}

// exact younger-than-target ledger (derivation in loop comment below)
__host__ __device__ constexpr int wait_for(int i) {
    return (i == 0 || i == 1) ? 16
         : (i == 2)           ? 20
         : (i == 14)          ? 16
         : (i == 15)          ? 4
         : (i & 1)            ? 20
         : 24;
}

__global__ __launch_bounds__(64, 1)
void conv_vgather_kernel(const float* __restrict__ x, const float* __restrict__ W,
                         const float* __restrict__ bias, const int* __restrict__ kernel2,
                         float* __restrict__ out)
{
    __shared__ __align__(16) int lds_idx[32 * 4];   // 32 sites x 4 taps

    const int lane = threadIdx.x;          // 64 threads = 1 wave
    const int bi   = blockIdx.x;
    // R10 locality ordering: XCD (=bi%8) <-> batch-group, two temporal halves
    const int half = bi >> 10;             // 0: bg 0-7, 1: bg 8-15
    const int r    = bi & 1023;
    const int bgl  = r & 7;                // XCD binding = bi%8
    const int sg   = r >> 3;               // 128 site-groups of 32 sites
    const int bg   = bgl + half * 8;
    const int n0   = sg * 32;
    const int b0   = bg * 4;

    const int c  = lane & 15;              // MFMA col = (site sl, batch bb)
    const int q  = lane >> 4;              // k-quad; D row (o) = q*4+reg
    const int sl = c >> 2;
    const int bb = c & 3;

    // ---- stage this block's kernel2 slice into LDS (single wave: ds_write
    //      then ds_read is wave-coherent; compiler inserts lgkmcnt)
    if (lane < 32)
        ((int4*)lds_idx)[lane] = ((const int4*)kernel2)[n0 + lane];

    // ---- A-fragments of W in registers (128 VGPRs)
    // A[m=c][k=q*8+j] for o = t*16+c, K32-chunk s = tap*2 + hs: aw[t][s]
    bf16x8 aw[4][8];
    #pragma unroll
    for (int t = 0; t < 4; ++t)
        #pragma unroll
        for (int s = 0; s < 8; ++s) {
            uint32_t* ap = (uint32_t*)&aw[t][s];
            #pragma unroll
            for (int u = 0; u < 4; ++u) {
                float f0 = W[(size_t)(s*32 + q*8 + 2*u    ) * OUT_DIM + t*16 + c];
                float f1 = W[(size_t)(s*32 + q*8 + 2*u + 1) * OUT_DIM + t*16 + c];
                ap[u] = pack2_bf16(f0, f1);
            }
        }

    f32x4 bias_r[4];
    #pragma unroll
    for (int t = 0; t < 4; ++t) bias_r[t] = *(const f32x4*)&bias[t*16 + q*4];

    // per-lane gather base: this lane's batch plane + its k-quad channels
    const float* gxb = x + (size_t)(b0 + bb) * (N_SITES * C_DIM) + q * 8;

    // drain prologue loads: vmcnt queue must start empty for exact counting
    wait_vmcnt<0>();
    __builtin_amdgcn_sched_barrier(0);

    // 3 rotating staging buffers, 8 x f32x4 each (32 VGPRs): half-tile i
    // (phase pp=i>>1, taps {2h,2h+1}, h=i&1) in buf(i%3).
    // buf[tl*4 + j]: tap (2h+tl); j = {0:+0B, 1:+16B, 2:+128B, 3:+144B}
    //   = chunk hs=j>>1, floats q*8+{0..3 | 4..7} of that chunk.
    f32x4 buf0[8], buf1[8], buf2[8];

    // issue: 8 loads for half-tile i into buf (buf indices all literal).
    // idx via ds_read (lgkmcnt) — vmcnt queue stays loads+stores only.
    auto issue = [&](f32x4* buf, int i) {
        const int2 tk = *(const int2*)&lds_idx[(i >> 1) * 16 + sl * 4 + (i & 1) * 2];
        const float* p0 = gxb + (size_t)(uint32_t)tk.x * C_DIM;  // tap 2h
        const float* p1 = gxb + (size_t)(uint32_t)tk.y * C_DIM;  // tap 2h+1
        gld16<0>(buf[0], p0); gld16<16>(buf[1], p0);
        gld16<128>(buf[2], p0); gld16<144>(buf[3], p0);
        gld16<0>(buf[4], p1); gld16<16>(buf[5], p1);
        gld16<128>(buf[6], p1); gld16<144>(buf[7], p1);
    };

    auto comp = [&](const f32x4* buf, int h, f32x4* acc) {
        #pragma unroll
        for (int tl = 0; tl < 2; ++tl)
            #pragma unroll
            for (int hs = 0; hs < 2; ++hs) {
                const f32x4 xa = buf[tl*4 + hs*2];
                const f32x4 xb = buf[tl*4 + hs*2 + 1];
                bf16x8 bf;
                uint32_t* bp = (uint32_t*)&bf;
                bp[0] = pack2_bf16(xa[0], xa[1]);
                bp[1] = pack2_bf16(xa[2], xa[3]);
                bp[2] = pack2_bf16(xb[0], xb[1]);
                bp[3] = pack2_bf16(xb[2], xb[3]);
                #pragma unroll
                for (int t = 0; t < 4; ++t)
                    acc[t] = __builtin_amdgcn_mfma_f32_16x16x32_bf16(
                        aw[t][h*4 + tl*2 + hs], bf, acc[t], 0, 0, 0);
            }
    };

    auto dostore = [&](int p, const f32x4* acc) {
        // store: D col=c -> (site n0+p*4+sl, batch b0+bb); o = t*16+q*4+r
        const int n = n0 + p * 4 + sl;
        float* op = out + ((size_t)(b0 + bb) * N_SITES + n) * OUT_DIM + q * 4;
        #pragma unroll
        for (int t = 0; t < 4; ++t)
            *(f32x4*)(op + t*16) = acc[t] + bias_r[t];
    };

    issue(buf0, 0);
    issue(buf1, 1);
    issue(buf2, 2);

    // 16 half-tiles; comp H(i) from buf(i%3), then refill it with H(i+3).
    // Op order: L0 L1 L2 | i: wait, comp, [i<=12: issue L(i+3)], [odd: S].
    // Younger-than-L(i) ledger: i0: L1,L2=16; i1: L2,L3=16; i2: L3,L4,S0=20;
    // odd 3..13: L,S,L=20; even 4..12: S,L,L,S=24; i14: S5,L15,S6=16; i15: S6=4.
    f32x4 acc[4];

    #define STEP(i)                                                           \
    {                                                                         \
        wait_vmcnt<wait_for(i)>();                                            \
        __builtin_amdgcn_sched_barrier(0);                                    \
        f32x4* bcur = ((i) % 3 == 0) ? buf0 : ((i) % 3 == 1) ? buf1 : buf2;   \
        if (((i) & 1) == 0) {                                                 \
            acc[0] = (f32x4){0.f,0.f,0.f,0.f};                                \
            acc[1] = (f32x4){0.f,0.f,0.f,0.f};                                \
            acc[2] = (f32x4){0.f,0.f,0.f,0.f};                                \
            acc[3] = (f32x4){0.f,0.f,0.f,0.f};                                \
        }                                                                     \
        comp(bcur, (i) & 1, acc);                                             \
        if ((i) <= 12) issue(bcur, (i) + 3);                                  \
        if ((i) & 1) dostore((i) >> 1, acc);                                  \
    }

    STEP(0);  STEP(1);  STEP(2);  STEP(3);
    STEP(4);  STEP(5);  STEP(6);  STEP(7);
    STEP(8);  STEP(9);  STEP(10); STEP(11);
    STEP(12); STEP(13); STEP(14); STEP(15);

    #undef STEP
}

extern "C" void kernel_launch(void* const* d_in, const int* in_sizes, int n_in,
                              void* d_out, int out_size, void* d_ws, size_t ws_size,
                              hipStream_t stream) {
    const float* x       = (const float*)d_in[0];
    const float* W       = (const float*)d_in[1];
    const float* bias    = (const float*)d_in[2];
    const int*   kernel2 = (const int*)d_in[3];
    float* out = (float*)d_out;

    // 2048 single-wave blocks; two temporal halves of 1024 (= 4/CU, full
    // device generation); XCD k <- batch-group bgl=k within each half.
    conv_vgather_kernel<<<2048, 64, 0, stream>>>(x, W, bias, kernel2, out);
}

// Round 9
// 140.159 us; speedup vs baseline: 1.0420x; 1.0420x over previous
//
#include <hip/hip_runtime.h>
#include <stdint.h>

// conv_59700045414486: y[b,n,o] = sum_{k,c} x[b, kernel2[n,k], c] * W[k,c,o] + bias[o]
// B=64, N=4096, C=64, OUT=64, K2=4
//
// R14: R13's null (register-path == LDS-DMA path == ~50-57us) plus the
// cross-round invariant (~1 line / 8cy / CU regardless of waves, queue depth,
// coalescing) points at a per-CU in-flight-line cap (MSHR-style) as the wall.
// Open question: do the DMA engine and the vector-load path share that pool?
// Experiment: drive BOTH simultaneously — per half-tile, tap A via
// global_load_lds (R11's coalesced+swizzled form), tap B via per-lane
// global_load_dwordx4 into registers (R13's form). Both count in the same
// per-wave vmcnt in issue order -> the proven 8-ops/HT ledger is unchanged.
//   - LDS: 3 rotating 4KB tap-A tile slots + 512B idx = 12.8KB.
//   - regs: 3 rotating 4xf32x4 tap-B buffers (48 VGPRs).
//   - rule-18 discipline: sched_barrier(0) after every counted wait;
//     16 steps macro-expanded (rule-20: all indices literal).
//   - R10 locality mapping kept (XCD k <-> batch-group).
// If paths independent: ~30-37us dispatch. If shared: ~50-57 (then attack
// request COUNT next: bf16 precast halves lines/row).

#define N_SITES  4096
#define C_DIM    64
#define OUT_DIM  64

typedef __attribute__((ext_vector_type(8))) short bf16x8;
typedef __attribute__((ext_vector_type(4))) float f32x4;

__device__ __forceinline__ uint32_t pack2_bf16(float f0, float f1) {
    uint32_t u0 = __float_as_uint(f0) + 0x8000u;
    uint32_t u1 = __float_as_uint(f1) + 0x8000u;
    return __builtin_amdgcn_perm(u1, u0, 0x07060302u);  // [bf16(f1)|bf16(f0)]
}

template<int N> __device__ __forceinline__ void wait_vmcnt() {
    asm volatile("s_waitcnt vmcnt(%0)" :: "n"(N) : "memory");
}

// async 16B/lane global->LDS DMA; LDS dst = M0 + lane*16 (wave-uniform M0)
__device__ __forceinline__ void gll16(const float* p, uint32_t m0v) {
    asm volatile("s_mov_b32 m0, %1\n\t"
                 "global_load_lds_dwordx4 %0, off"
                 :: "v"(p), "s"(m0v) : "memory");
}

// per-lane 16B global load into explicit VGPRs; manual vmcnt discipline.
template<int OFF>
__device__ __forceinline__ void gld16(f32x4& d, const float* p) {
    asm volatile("global_load_dwordx4 %0, %1, off offset:%2"
                 : "=v"(d) : "v"(p), "n"(OFF) : "memory");
}

// exact younger-than-target ledger (8 ops/HT: 4 DMA + 4 vector; 4 stores
// per odd step). Derivation re-verified in R14 notes; structure == R13.
__host__ __device__ constexpr int wait_for(int i) {
    return (i == 0 || i == 1) ? 16
         : (i == 2)           ? 20
         : (i == 14)          ? 16
         : (i == 15)          ? 4
         : (i & 1)            ? 20
         : 24;
}

__global__ __launch_bounds__(64, 1)
void conv_dual_kernel(const float* __restrict__ x, const float* __restrict__ W,
                      const float* __restrict__ bias, const int* __restrict__ kernel2,
                      float* __restrict__ out)
{
    // [0,12288): 3 rotating 4KB tap-A tile slots; [12288,12800): idx (32 int4)
    __shared__ __align__(1024) uint8_t lds_raw[12800];

    const int lane = threadIdx.x;          // 64 threads = 1 wave
    const int bi   = blockIdx.x;
    // R10 locality ordering: XCD (=bi%8) <-> batch-group, two temporal halves
    const int half = bi >> 10;             // 0: bg 0-7, 1: bg 8-15
    const int r    = bi & 1023;
    const int bgl  = r & 7;                // XCD binding = bi%8
    const int sg   = r >> 3;               // 128 site-groups of 32 sites
    const int bg   = bgl + half * 8;
    const int n0   = sg * 32;
    const int b0   = bg * 4;

    const int c  = lane & 15;              // MFMA col = (site sl, batch bb)
    const int q  = lane >> 4;              // k-quad; D row (o) = q*4+reg
    const int sl = c >> 2;
    const int bb = c & 3;

    // DMA lane roles (tap-A path): quarter-wave g = batch plane; u = 16B unit
    const int g = lane >> 4;
    const int u = lane & 15;

    // ---- stage this block's kernel2 slice into LDS
    if (lane < 32)
        ((int4*)(lds_raw + 12288))[lane] = ((const int4*)kernel2)[n0 + lane];
    const int* lds_idx = (const int*)(lds_raw + 12288);

    // ---- A-fragments of W in registers (128 VGPRs)
    // A[m=c][k=q*8+j] for o = t*16+c, K32-chunk s = tap*2 + hs: aw[t][s]
    bf16x8 aw[4][8];
    #pragma unroll
    for (int t = 0; t < 4; ++t)
        #pragma unroll
        for (int s = 0; s < 8; ++s) {
            uint32_t* ap = (uint32_t*)&aw[t][s];
            #pragma unroll
            for (int uu = 0; uu < 4; ++uu) {
                float f0 = W[(size_t)(s*32 + q*8 + 2*uu    ) * OUT_DIM + t*16 + c];
                float f1 = W[(size_t)(s*32 + q*8 + 2*uu + 1) * OUT_DIM + t*16 + c];
                ap[uu] = pack2_bf16(f0, f1);
            }
        }

    f32x4 bias_r[4];
    #pragma unroll
    for (int t = 0; t < 4; ++t) bias_r[t] = *(const f32x4*)&bias[t*16 + q*4];

    // tap-A DMA source base: batch plane (b0+g), source-swizzled within-row
    // (LDS 32B pos p=u>>1 receives global chunk p^g; +16B half (u&1))
    const float* gxn = x + (size_t)(b0 + g) * (N_SITES * C_DIM)
                     + (size_t)((((u >> 1) ^ g) * 8) + (u & 1) * 4);
    // tap-B vector base: this lane's batch plane + its k-quad channels
    const float* gxb = x + (size_t)(b0 + bb) * (N_SITES * C_DIM) + q * 8;

    const uint32_t lds0 =
        __builtin_amdgcn_readfirstlane((uint32_t)(uintptr_t)lds_raw);

    // drain prologue loads: vmcnt queue must start empty for exact counting
    wait_vmcnt<0>();
    __builtin_amdgcn_sched_barrier(0);

    // 3 rotating tap-B reg buffers (4 x f32x4): buf[hs*2+j]: chunk hs,
    // floats q*8+{0..3 | 4..7}.
    f32x4 vb0[4], vb1[4], vb2[4];

    // half-tile i: phase pp=i>>1, h=i&1; tap A = 2h (DMA->LDS slot i%3),
    // tap B = 2h+1 (vector->regs buf i%3).
    // tap-A slot layout: site slp at +slp*1024; within: quarter g at g*256,
    // 32B chunks permuted by ^g (source-swizzled).
    auto issue = [&](f32x4* vb, int i) {
        const int pp = i >> 1, h = i & 1;
        const int* ib = lds_idx + pp * 16;
        const uint32_t m0s = lds0 + (uint32_t)(i % 3) * 4096;
        #pragma unroll
        for (int slp = 0; slp < 4; ++slp) {
            const int nka = ib[slp * 4 + 2 * h];           // tap 2h, site slp
            const float* rowa = gxn + (size_t)(uint32_t)nka * C_DIM;
            gll16(rowa, m0s + (uint32_t)slp * 1024);
        }
        const int nkb = ib[sl * 4 + 2 * h + 1];            // tap 2h+1, site sl
        const float* rowb = gxb + (size_t)(uint32_t)nkb * C_DIM;
        gld16<0>(vb[0], rowb);   gld16<16>(vb[1], rowb);
        gld16<128>(vb[2], rowb); gld16<144>(vb[3], rowb);
    };

    // compute half-tile i: tap A from LDS (R11 readback), tap B from regs.
    auto comp = [&](const f32x4* vb, int i, f32x4* acc) {
        const uint32_t tb = (uint32_t)(i % 3) * 4096;
        const int h = i & 1;
        #pragma unroll
        for (int hs = 0; hs < 2; ++hs) {       // tap A = 2h: aw s = 4h+hs
            const uint8_t* pb = lds_raw + tb + (uint32_t)c * 256
                              + (uint32_t)(((hs * 4 + q) ^ (c & 3)) * 32);
            f32x4 xa = *(const f32x4*)(pb);
            f32x4 xb = *(const f32x4*)(pb + 16);
            bf16x8 bf;
            uint32_t* bp = (uint32_t*)&bf;
            bp[0] = pack2_bf16(xa[0], xa[1]);
            bp[1] = pack2_bf16(xa[2], xa[3]);
            bp[2] = pack2_bf16(xb[0], xb[1]);
            bp[3] = pack2_bf16(xb[2], xb[3]);
            #pragma unroll
            for (int t = 0; t < 4; ++t)
                acc[t] = __builtin_amdgcn_mfma_f32_16x16x32_bf16(
                    aw[t][h*4 + hs], bf, acc[t], 0, 0, 0);
        }
        #pragma unroll
        for (int hs = 0; hs < 2; ++hs) {       // tap B = 2h+1: aw s = 4h+2+hs
            const f32x4 xa = vb[hs*2];
            const f32x4 xb = vb[hs*2 + 1];
            bf16x8 bf;
            uint32_t* bp = (uint32_t*)&bf;
            bp[0] = pack2_bf16(xa[0], xa[1]);
            bp[1] = pack2_bf16(xa[2], xa[3]);
            bp[2] = pack2_bf16(xb[0], xb[1]);
            bp[3] = pack2_bf16(xb[2], xb[3]);
            #pragma unroll
            for (int t = 0; t < 4; ++t)
                acc[t] = __builtin_amdgcn_mfma_f32_16x16x32_bf16(
                    aw[t][h*4 + 2 + hs], bf, acc[t], 0, 0, 0);
        }
    };

    auto dostore = [&](int p, const f32x4* acc) {
        // store: D col=c -> (site n0+p*4+sl, batch b0+bb); o = t*16+q*4+r
        const int n = n0 + p * 4 + sl;
        float* op = out + ((size_t)(b0 + bb) * N_SITES + n) * OUT_DIM + q * 4;
        #pragma unroll
        for (int t = 0; t < 4; ++t)
            *(f32x4*)(op + t*16) = acc[t] + bias_r[t];
    };

    issue(vb0, 0);
    issue(vb1, 1);
    issue(vb2, 2);

    // 16 half-tiles; comp H(i) from slot/buf (i%3), refill with H(i+3).
    // Ledger (8 ops/HT, 4 stores/odd step): i0,i1: 16; i2: 20; odd 3..13: 20;
    // even 4..12: 24; i14: 16; i15: 4.   (re-derived; matches R13 structure)
    f32x4 acc[4];

    #define STEP(i)                                                           \
    {                                                                         \
        wait_vmcnt<wait_for(i)>();                                            \
        __builtin_amdgcn_sched_barrier(0);                                    \
        f32x4* bcur = ((i) % 3 == 0) ? vb0 : ((i) % 3 == 1) ? vb1 : vb2;      \
        if (((i) & 1) == 0) {                                                 \
            acc[0] = (f32x4){0.f,0.f,0.f,0.f};                                \
            acc[1] = (f32x4){0.f,0.f,0.f,0.f};                                \
            acc[2] = (f32x4){0.f,0.f,0.f,0.f};                                \
            acc[3] = (f32x4){0.f,0.f,0.f,0.f};                                \
        }                                                                     \
        comp(bcur, (i), acc);                                                 \
        if ((i) <= 12) issue(bcur, (i) + 3);                                  \
        if ((i) & 1) dostore((i) >> 1, acc);                                  \
    }

    STEP(0);  STEP(1);  STEP(2);  STEP(3);
    STEP(4);  STEP(5);  STEP(6);  STEP(7);
    STEP(8);  STEP(9);  STEP(10); STEP(11);
    STEP(12); STEP(13); STEP(14); STEP(15);

    #undef STEP
}

extern "C" void kernel_launch(void* const* d_in, const int* in_sizes, int n_in,
                              void* d_out, int out_size, void* d_ws, size_t ws_size,
                              hipStream_t stream) {
    const float* x       = (const float*)d_in[0];
    const float* W       = (const float*)d_in[1];
    const float* bias    = (const float*)d_in[2];
    const int*   kernel2 = (const int*)d_in[3];
    float* out = (float*)d_out;

    // 2048 single-wave blocks; two temporal halves of 1024 (= 4/CU, full
    // device generation); XCD k <- batch-group bgl=k within each half.
    conv_dual_kernel<<<2048, 64, 0, stream>>>(x, W, bias, kernel2, out);
}

// Round 10
// 134.557 us; speedup vs baseline: 1.0854x; 1.0416x over previous
//
#include <hip/hip_runtime.h>
#include <stdint.h>

// conv_59700045414486: y[b,n,o] = sum_{k,c} x[b, kernel2[n,k], c] * W[k,c,o] + bias[o]
// B=64, N=4096, C=64, OUT=64, K2=4
//
// R15: per-CU gather line rate is pinned at ~14.6cy/128B-line across every
// config (R5..R14: waves, queue depth, coalescing, path choice) -> small HW
// in-flight-line cap per wave; software queues are backlog. Only remaining
// lever: LINE COUNT. Precast x to bf16 (one streaming pass into d_ws,
// 64MB->32MB) so each gathered row is 128B = ONE line: halves gather lines.
// Bonus: main loop loses all 32 pack2_bf16/HT (LDS holds ready MFMA
// fragments; one ds_read_b128 each) -> VALU ~3x down.
//   - gather kernel: R11 skeleton, 4 DMA instr/HT (8 rows via 8-lane
//     half-quarters), source-XOR-swizzle (unit (l&7)^hq) so readback is
//     <=2-way bank conflict; 3 rotating 4KB slots; exact ledger (re-derived);
//     R10 XCD<->batch-group pinning kept.
//   - precast kernel: grid-stride f32x8 -> bf16x8, ~96MB traffic ~10-15us.
//   - fallback: R11 f32 kernel if ws_size < 32MB.

#define N_SITES  4096
#define C_DIM    64
#define OUT_DIM  64

typedef __attribute__((ext_vector_type(8))) short bf16x8;
typedef __attribute__((ext_vector_type(4))) float f32x4;

__device__ __forceinline__ uint32_t pack2_bf16(float f0, float f1) {
    uint32_t u0 = __float_as_uint(f0) + 0x8000u;
    uint32_t u1 = __float_as_uint(f1) + 0x8000u;
    return __builtin_amdgcn_perm(u1, u0, 0x07060302u);  // [bf16(f1)|bf16(f0)]
}

template<int N> __device__ __forceinline__ void wait_vmcnt() {
    asm volatile("s_waitcnt vmcnt(%0)" :: "n"(N) : "memory");
}

// async 16B/lane global->LDS DMA; LDS dst = M0 + lane*16 (wave-uniform M0)
__device__ __forceinline__ void gll16(const void* p, uint32_t m0v) {
    asm volatile("s_mov_b32 m0, %1\n\t"
                 "global_load_lds_dwordx4 %0, off"
                 :: "v"(p), "s"(m0v) : "memory");
}

// ---------------- precast: x f32 [B][N][C] -> bf16 (u32-packed) in ws ------
__global__ __launch_bounds__(256, 1)
void precast_kernel(const float* __restrict__ x, uint32_t* __restrict__ xb)
{
    const uint32_t n8 = 64u * 4096u * 64u / 8u;   // 2,097,152 groups of 8
    for (uint32_t i = blockIdx.x * 256 + threadIdx.x; i < n8;
         i += gridDim.x * 256) {
        const f32x4* p = (const f32x4*)x + 2 * (size_t)i;
        f32x4 a = p[0], b = p[1];
        uint4 o;
        o.x = pack2_bf16(a[0], a[1]); o.y = pack2_bf16(a[2], a[3]);
        o.z = pack2_bf16(b[0], b[1]); o.w = pack2_bf16(b[2], b[3]);
        ((uint4*)xb)[i] = o;
    }
}

// ---------------- bf16 gather kernel ---------------------------------------
// ledger: 4 loads/HT, 4 stores/odd step, prologue H0..H2 (12 ops).
// op order: s0:L3 | s1:L4,S0 | s2:L5 | s3:L6,S1 | ... | s12:L15 | s13:S6 |
// younger-than-L(i): i0,i1:8; i2,i3:12; even4..12:16; odd5..13:12; i14:12; i15:4
__host__ __device__ constexpr int wait_for(int i) {
    return (i <= 1) ? 8 : (i == 2 || i == 3) ? 12
         : (i == 15) ? 4 : (i == 14) ? 12
         : (i & 1) ? 12 : 16;
}

__global__ __launch_bounds__(64, 1)
void conv_bf16_kernel(const uint8_t* __restrict__ xb, const float* __restrict__ W,
                      const float* __restrict__ bias, const int* __restrict__ kernel2,
                      float* __restrict__ out)
{
    // [0,12288): 3 rotating 4KB HT slots; [12288,12800): idx (32 int4)
    __shared__ __align__(1024) uint8_t lds_raw[12800];

    const int lane = threadIdx.x;          // 64 threads = 1 wave
    const int bi   = blockIdx.x;
    // R10 locality: XCD (=bi%8) <-> batch-group, two temporal halves
    const int half = bi >> 10;
    const int r    = bi & 1023;
    const int bgl  = r & 7;
    const int sg   = r >> 3;
    const int bg   = bgl + half * 8;
    const int n0   = sg * 32;
    const int b0   = bg * 4;

    const int c  = lane & 15;              // MFMA col = (site sl, batch bb)
    const int q  = lane >> 4;              // k-quad; D row (o) = q*4+reg
    const int sl = c >> 2;
    const int bb = c & 3;

    // DMA lane roles: half-quarter hq = one bf16 row (batch hq>>1, s_off hq&1)
    const int hq = lane >> 3;              // 0..7
    const int lm = lane & 7;               // 16B unit within 128B row

    if (lane < 32)
        ((int4*)(lds_raw + 12288))[lane] = ((const int4*)kernel2)[n0 + lane];
    const int* lds_idx = (const int*)(lds_raw + 12288);

    // ---- A-fragments of W in registers (128 VGPRs)
    bf16x8 aw[4][8];
    #pragma unroll
    for (int t = 0; t < 4; ++t)
        #pragma unroll
        for (int s = 0; s < 8; ++s) {
            uint32_t* ap = (uint32_t*)&aw[t][s];
            #pragma unroll
            for (int u = 0; u < 4; ++u) {
                float f0 = W[(size_t)(s*32 + q*8 + 2*u    ) * OUT_DIM + t*16 + c];
                float f1 = W[(size_t)(s*32 + q*8 + 2*u + 1) * OUT_DIM + t*16 + c];
                ap[u] = pack2_bf16(f0, f1);
            }
        }

    f32x4 bias_r[4];
    #pragma unroll
    for (int t = 0; t < 4; ++t) bias_r[t] = *(const f32x4*)&bias[t*16 + q*4];

    // per-lane DMA source base: batch plane (b0 + hq>>1); source-swizzled
    // unit (lm ^ hq) so LDS slot (row hq, unit lm) holds global unit lm^hq.
    const uint8_t* gsrc = xb + (size_t)(b0 + (hq >> 1)) * (N_SITES * 128)
                        + (size_t)((lm ^ hq) * 16);

    const uint32_t lds0 =
        __builtin_amdgcn_readfirstlane((uint32_t)(uintptr_t)lds_raw);

    wait_vmcnt<0>();
    __builtin_amdgcn_sched_barrier(0);

    // half-tile i (phase i>>1, taps {2h,2h+1}): 4 instrs; instr j covers
    // tap 2h+(j>>1), site-pair (j&1)*2+{0,1}, all 4 batches (8 rows).
    // LDS slot (i%3)*4096: instr j at +j*1024, row hq at +hq*128.
    auto issue = [&](int i) {
        const int h = i & 1, pp = i >> 1;
        const int* ib = lds_idx + pp * 16;
        const uint32_t m0s = lds0 + (uint32_t)(i % 3) * 4096;
        #pragma unroll
        for (int j = 0; j < 4; ++j) {
            const int tap = 2 * h + (j >> 1);
            const int sp  = (j & 1) * 2;
            const int nk0 = ib[(sp    ) * 4 + tap];
            const int nk1 = ib[(sp + 1) * 4 + tap];
            const int nk  = (hq & 1) ? nk1 : nk0;
            gll16(gsrc + (size_t)(uint32_t)nk * 128,
                  m0s + (uint32_t)j * 1024);
        }
    };

    // comp: lane (q,c) reads bf16x8 fragment per (tl,hs) directly from LDS.
    // row rr = bb*2 + (sl&1); slot j = tl*2 + (sl>>1); unit (hs*4+q)^rr.
    auto comp = [&](int i, f32x4* acc) {
        const uint32_t tb = (uint32_t)(i % 3) * 4096;
        const int h = i & 1;
        const uint32_t rr = (uint32_t)(bb * 2 + (sl & 1));
        #pragma unroll
        for (int tl = 0; tl < 2; ++tl) {
            const uint32_t js = (uint32_t)(tl * 2 + (sl >> 1));
            #pragma unroll
            for (int hs = 0; hs < 2; ++hs) {
                const uint32_t uw = ((uint32_t)(hs * 4 + q)) ^ rr;
                const bf16x8 bf = *(const bf16x8*)(lds_raw + tb + js * 1024
                                                   + rr * 128 + uw * 16);
                #pragma unroll
                for (int t = 0; t < 4; ++t)
                    acc[t] = __builtin_amdgcn_mfma_f32_16x16x32_bf16(
                        aw[t][h*4 + tl*2 + hs], bf, acc[t], 0, 0, 0);
            }
        }
    };

    auto dostore = [&](int p, const f32x4* acc) {
        const int n = n0 + p * 4 + sl;
        float* op = out + ((size_t)(b0 + bb) * N_SITES + n) * OUT_DIM + q * 4;
        #pragma unroll
        for (int t = 0; t < 4; ++t)
            *(f32x4*)(op + t*16) = acc[t] + bias_r[t];
    };

    issue(0);
    issue(1);
    issue(2);

    f32x4 acc[4];

    #define STEP(i)                                                           \
    {                                                                         \
        wait_vmcnt<wait_for(i)>();                                            \
        __builtin_amdgcn_sched_barrier(0);                                    \
        if (((i) & 1) == 0) {                                                 \
            acc[0] = (f32x4){0.f,0.f,0.f,0.f};                                \
            acc[1] = (f32x4){0.f,0.f,0.f,0.f};                                \
            acc[2] = (f32x4){0.f,0.f,0.f,0.f};                                \
            acc[3] = (f32x4){0.f,0.f,0.f,0.f};                                \
        }                                                                     \
        comp((i), acc);                                                       \
        if ((i) <= 12) issue((i) + 3);                                        \
        if ((i) & 1) dostore((i) >> 1, acc);                                  \
    }

    STEP(0);  STEP(1);  STEP(2);  STEP(3);
    STEP(4);  STEP(5);  STEP(6);  STEP(7);
    STEP(8);  STEP(9);  STEP(10); STEP(11);
    STEP(12); STEP(13); STEP(14); STEP(15);

    #undef STEP
}

// ---------------- fallback: R11 f32 kernel (proven, ~50us) -----------------
__global__ __launch_bounds__(64, 1)
void conv_f32_kernel(const float* __restrict__ x, const float* __restrict__ W,
                     const float* __restrict__ bias, const int* __restrict__ kernel2,
                     float* __restrict__ out)
{
    __shared__ __align__(1024) uint8_t lds_raw[33280];
    const int lane = threadIdx.x;
    const int bi   = blockIdx.x;
    const int half = bi >> 10;
    const int r    = bi & 1023;
    const int bgl  = r & 7;
    const int sg   = r >> 3;
    const int bg   = bgl + half * 8;
    const int n0   = sg * 32;
    const int b0   = bg * 4;
    const int c  = lane & 15;
    const int q  = lane >> 4;
    const int sl = c >> 2;
    const int bb = c & 3;
    const int g  = lane >> 4;
    const int u  = lane & 15;

    if (lane < 32) {
        int4 iv = ((const int4*)kernel2)[n0 + lane];
        *(int4*)(lds_raw + 32768 + lane * 16) = iv;
    }

    bf16x8 aw[4][8];
    #pragma unroll
    for (int t = 0; t < 4; ++t)
        #pragma unroll
        for (int s = 0; s < 8; ++s) {
            uint32_t* ap = (uint32_t*)&aw[t][s];
            #pragma unroll
            for (int uu = 0; uu < 4; ++uu) {
                float f0 = W[(size_t)(s*32 + q*8 + 2*uu    ) * OUT_DIM + t*16 + c];
                float f1 = W[(size_t)(s*32 + q*8 + 2*uu + 1) * OUT_DIM + t*16 + c];
                ap[uu] = pack2_bf16(f0, f1);
            }
        }

    f32x4 bias_r[4];
    #pragma unroll
    for (int t = 0; t < 4; ++t) bias_r[t] = *(const f32x4*)&bias[t*16 + q*4];

    const float* gxn = x + (size_t)(b0 + g) * (N_SITES * C_DIM)
                     + (size_t)((((u >> 1) ^ g) * 8) + (u & 1) * 4);
    const uint32_t lds0 =
        __builtin_amdgcn_readfirstlane((uint32_t)(uintptr_t)lds_raw);

    wait_vmcnt<0>();

    auto issue_ht = [&](int i) {
        const int pp = i >> 1, h = i & 1;
        const int* ibase = (const int*)(lds_raw + 32768 + pp * 64);
        const uint32_t m0s = lds0 + (uint32_t)(i & 3) * 8192;
        #pragma unroll
        for (int kl = 0; kl < 2; ++kl)
            #pragma unroll
            for (int slp = 0; slp < 4; ++slp) {
                const int nk = ibase[slp * 4 + 2 * h + kl];
                gll16(gxn + (size_t)(uint32_t)nk * C_DIM,
                      m0s + (uint32_t)kl * 4096 + (uint32_t)slp * 1024);
            }
    };

    auto comp_ht = [&](int i, f32x4* acc) {
        const uint32_t tb = (uint32_t)(i & 3) * 8192;
        const int hb = (i & 1) * 4;
        #pragma unroll
        for (int kl = 0; kl < 2; ++kl)
        #pragma unroll
        for (int hs = 0; hs < 2; ++hs) {
            const uint8_t* pb = lds_raw + tb + (uint32_t)kl * 4096
                              + (uint32_t)c * 256
                              + (uint32_t)((((hs * 4 + q) ^ (c & 3)) * 32));
            f32x4 xa = *(const f32x4*)(pb);
            f32x4 xb = *(const f32x4*)(pb + 16);
            bf16x8 bf;
            uint32_t* bp = (uint32_t*)&bf;
            bp[0] = pack2_bf16(xa[0], xa[1]);
            bp[1] = pack2_bf16(xa[2], xa[3]);
            bp[2] = pack2_bf16(xb[0], xb[1]);
            bp[3] = pack2_bf16(xb[2], xb[3]);
            #pragma unroll
            for (int t = 0; t < 4; ++t)
                acc[t] = __builtin_amdgcn_mfma_f32_16x16x32_bf16(
                    aw[t][hb + kl * 2 + hs], bf, acc[t], 0, 0, 0);
        }
    };

    issue_ht(0); issue_ht(1); issue_ht(2); issue_ht(3);

    #pragma unroll
    for (int p = 0; p < 8; ++p) {
        f32x4 acc[4];
        #pragma unroll
        for (int t = 0; t < 4; ++t) acc[t] = (f32x4){0.f, 0.f, 0.f, 0.f};

        if      (p == 0) wait_vmcnt<24>();
        else if (p == 1) wait_vmcnt<28>();
        else if (p == 7) wait_vmcnt<16>();
        else             wait_vmcnt<32>();
        comp_ht(2*p, acc);
        if (p <= 5) issue_ht(2*p + 4);

        if      (p == 0) wait_vmcnt<24>();
        else if (p == 1) wait_vmcnt<28>();
        else if (p == 6) wait_vmcnt<24>();
        else if (p == 7) wait_vmcnt<8>();
        else             wait_vmcnt<32>();
        comp_ht(2*p + 1, acc);
        if (p <= 5) issue_ht(2*p + 5);

        const int n = n0 + p*4 + sl;
        float* op = out + ((size_t)(b0 + bb) * N_SITES + n) * OUT_DIM + q*4;
        #pragma unroll
        for (int t = 0; t < 4; ++t)
            *(f32x4*)(op + t*16) = acc[t] + bias_r[t];
    }
}

extern "C" void kernel_launch(void* const* d_in, const int* in_sizes, int n_in,
                              void* d_out, int out_size, void* d_ws, size_t ws_size,
                              hipStream_t stream) {
    const float* x       = (const float*)d_in[0];
    const float* W       = (const float*)d_in[1];
    const float* bias    = (const float*)d_in[2];
    const int*   kernel2 = (const int*)d_in[3];
    float* out = (float*)d_out;

    const size_t need = (size_t)64 * 4096 * 64 * 2;   // 32MB bf16 x
    if (ws_size >= need && d_ws != nullptr) {
        precast_kernel<<<2048, 256, 0, stream>>>(x, (uint32_t*)d_ws);
        conv_bf16_kernel<<<2048, 64, 0, stream>>>((const uint8_t*)d_ws, W,
                                                  bias, kernel2, out);
    } else {
        conv_f32_kernel<<<2048, 64, 0, stream>>>(x, W, bias, kernel2, out);
    }
}